// Round 4
// baseline (416.500 us; speedup 1.0000x reference)
//
#include <hip/hip_runtime.h>
#include <math.h>

// Bayesian 2-layer LSTM (B=8192,T=100,I=24,H=64,H2=128) — two-kernel version.
//
// R9: trans-minimized packed pointwise + deeper x prefetch + 2x sample split.
// R8 profile: 286 us, VALU 60.6% of which ~75% is 1/8-rate transcendentals
// (96/thread/step). Changes:
// (1) lstm_pair: common-denominator form cn=(c*A*C+(cv-1)*B)*rcp(A*B*C),
//     h=(e-1)*rcp(D*E) with h-rcp paired across 2 elements ->
//     5 exp2 + 1.5 rcp per element (was 5+3). Clamps (|gate|<=14) make all
//     products overflow-safe; clamp error < 1e-6.
// (2) pointwise written on float ext_vector(2) so ISel emits v_pk_*_f32
//     (VOP3P) -> ~half the full-rate instruction count.
// (3) x loaded one full step ahead (x_{j+2} issued at step j) -> L3 latency
//     fully hidden across the barrier.
// (4) sample_kernel W2 work split 2x (4 values/thread, 116 blocks).

typedef __attribute__((ext_vector_type(8))) short short8;   // 8 bf16
typedef __attribute__((ext_vector_type(4))) float f32x4;
typedef __attribute__((ext_vector_type(2))) float f32x2;

#define MFMA16(a, b, c) __builtin_amdgcn_mfma_f32_16x16x32_bf16((a), (b), (c), 0, 0, 0)

// ---- d_ws layout (bytes) ----
// [0, 196608)        W2S : 12288 short8 frags, idx = (kk*4+g)*512 + tid
// [196608, 245760)   W1G : 3072 short8, u = slice*256+n (slice = kk*4+quad)
// [245760, 253284)   WF  : 1881 floats: b1[256] b2[512] fc1w[1024] fc2w[64]
//                          fc1b[8] fc2b[8] ow[8] ob[1]
#define WS_W1G_OFF 196608
#define WS_WF_OFF  245760

struct SampParams {
  const float* w1i[3]; const float* w1h[3]; const float* b1[3];
  const float* w2i[3]; const float* w2h[3]; const float* b2[3];
  const float* f1w[3]; const float* f1b[3];
  const float* f2w[3]; const float* f2b[3];
  const float* ow[3];  const float* ob[3];
  short* W2S; short* W1G; float* WF;
};

struct LstmParams {
  const float* input;
  const short* W2S; const short* W1G; const float* WF;
  float* out;
};

__device__ __forceinline__ float softplus_fast(float x) {
  // log(1+e^x) = ln2 * log2(1 + 2^(x*log2e))
  float e = __builtin_amdgcn_exp2f(1.44269504f * x);
  return 0.69314718f * __builtin_amdgcn_logf(1.0f + e);
}

__device__ __forceinline__ float samp(const float* const q[3], int idx) {
  return q[0][idx] + softplus_fast(q[1][idx]) * q[2][idx];
}

__device__ __forceinline__ short f2bf(float f) {
  unsigned u = __float_as_uint(f);
  unsigned r = (u + 0x7FFFu + ((u >> 16) & 1u)) >> 16;   // RNE
  return (short)r;
}

__device__ __forceinline__ unsigned cvt_pk_bf16(float lo, float hi) {
  unsigned r;
  asm("v_cvt_pk_bf16_f32 %0, %1, %2" : "=v"(r) : "v"(lo), "v"(hi));
  return r;
}

__device__ __forceinline__ f32x2 exp2v(f32x2 x) {
  f32x2 r;
  r.x = __builtin_amdgcn_exp2f(x.x);
  r.y = __builtin_amdgcn_exp2f(x.y);
  return r;
}

__device__ __forceinline__ f32x2 clampv(f32x2 x, float lim) {
  f32x2 lo = {-lim, -lim}, hi = {lim, lim};
  return __builtin_elementwise_min(__builtin_elementwise_max(x, lo), hi);
}

// Two LSTM elements (packed f32x2). Gates i,f,g,o -> new cell c, hidden h.
//   sig(i)=1/A, A=1+exp2(-K*i); tanh(g)=(cv-1)/(1+cv), cv=exp2(2K*g)
//   cn = c/B + (cv-1)/(A*(1+cv))  ->  (c*A*Cv + (cv-1)*B) * rcp(A*B*Cv)
//   h  = sig(o)*tanh(cn) = (e-1) * rcp(D*(1+e)),  e=exp2(2K*cn)
// h-rcp paired across the two elements: 1 rcp serves both.
// Per element: 5 exp2 + 1.5 rcp. Clamps keep every product < 3.4e38.
__device__ __forceinline__ void lstm_pair(f32x2 gi, f32x2 gf, f32x2 gg, f32x2 go,
                                          f32x2& c, f32x2& h) {
  const f32x2 kneg = {-1.44269504f, -1.44269504f};
  const f32x2 kpos = { 2.88539008f,  2.88539008f};
  const f32x2 one  = {1.0f, 1.0f};
  f32x2 a  = exp2v(clampv(gi * kneg, 20.2f));   // |gate| <= 14
  f32x2 b  = exp2v(clampv(gf * kneg, 20.2f));
  f32x2 cv = exp2v(clampv(gg * kpos, 40.4f));
  f32x2 d  = exp2v(clampv(go * kneg, 20.2f));
  f32x2 A = one + a, B = one + b, Cv = one + cv, D = one + d;
  f32x2 AC  = A * Cv;
  f32x2 Ncn = (cv - one) * B + c * AC;
  f32x2 Dcn = AC * B;                            // <= ~2.1e24
  f32x2 rq;
  rq.x = __builtin_amdgcn_rcpf(Dcn.x);
  rq.y = __builtin_amdgcn_rcpf(Dcn.y);
  c = Ncn * rq;                                  // new cell state
  f32x2 e  = exp2v(clampv(c * kpos, 40.4f));
  f32x2 Dh = D + D * e;                          // = D*E  <= ~1.8e18
  f32x2 Nh = e - one;                            // = E-2
  float R = __builtin_amdgcn_rcpf(Dh.x * Dh.y);  // product <= ~3e36, safe
  h.x = Nh.x * (R * Dh.y);
  h.y = Nh.y * (R * Dh.x);
}

// ---------------- kernel 1: sample all weights into d_ws ----------------
__global__ __launch_bounds__(256) void sample_kernel(SampParams p)
{
  int i = blockIdx.x * 256 + threadIdx.x;
  if (i < 24576) {
    // W2 frags: 2 threads per short8 frag (4 values each)
    int f = i >> 1, half = i & 1;
    int tid = f & 511, gg = (f >> 9) & 3, kk = f >> 11;
    int quad = (tid >> 4) & 3, col = tid & 15, v0 = (tid >> 6) * 16;
    int c = gg * 128 + v0 + col;
    int j0 = half * 4;
    unsigned o0, o1;
    {
      int k = kk * 32 + quad * 8 + j0;
      float x0 = (k < 64) ? samp(p.w2i, k * 512 + c) : samp(p.w2h, (k - 64) * 512 + c);
      ++k;
      float x1 = (k < 64) ? samp(p.w2i, k * 512 + c) : samp(p.w2h, (k - 64) * 512 + c);
      ++k;
      float x2 = (k < 64) ? samp(p.w2i, k * 512 + c) : samp(p.w2h, (k - 64) * 512 + c);
      ++k;
      float x3 = (k < 64) ? samp(p.w2i, k * 512 + c) : samp(p.w2h, (k - 64) * 512 + c);
      o0 = cvt_pk_bf16(x0, x1);
      o1 = cvt_pk_bf16(x2, x3);
    }
    *(uint2*)&p.W2S[f * 8 + j0] = make_uint2(o0, o1);
  } else if (i < 27648) {
    int u = i - 24576;
    int slice = u >> 8, n = u & 255;
    int k0 = (slice >> 2) * 32 + (slice & 3) * 8;
    short8 v;
#pragma unroll
    for (int j = 0; j < 8; ++j) {
      int k = k0 + j;
      float x = 0.0f;
      if (k < 24)       x = samp(p.w1i, k * 256 + n);
      else if (k >= 32) x = samp(p.w1h, (k - 32) * 256 + n);
      v[j] = f2bf(x);
    }
    *(short8*)&p.W1G[u * 8] = v;
  } else if (i < 29529) {
    int u = i - 27648;
    float x;
    if (u < 256)       x = samp(p.b1,  u);
    else if (u < 768)  x = samp(p.b2,  u - 256);
    else if (u < 1792) x = samp(p.f1w, u - 768);
    else if (u < 1856) x = samp(p.f2w, u - 1792);
    else if (u < 1864) x = samp(p.f1b, u - 1856);
    else if (u < 1872) x = samp(p.f2b, u - 1864);
    else if (u < 1880) x = samp(p.ow,  u - 1872);
    else               x = samp(p.ob,  0);
    p.WF[u] = x;
  }
}

// ---------------- kernel 2: fused 2-layer LSTM + head ----------------
// LDS pool:
//   [0,49152)      W1L : W1cat bf16 (3072 short8)
//   [49152,62464)  A1  : 2 buf x (32 x 104 shorts) [x(24)|pad(8)|h1(64)]
//   [62464,79872)  A2  : 2 buf x (32 x 136 shorts) [h2(128)|pad]
// Head phase aliases [0,...) : H2 32x132 f32, FC1W, FC2W, FB1/FB2/OW/OB, X1, X2

__global__ __launch_bounds__(512, 2)
void blstm_kernel(LstmParams p)
{
  __shared__ __align__(16) unsigned char pool[79872];
  short* const W1L = (short*)pool;
  short* const A1b = (short*)(pool + 49152);   // 2 x 3328 shorts
  short* const A2b = (short*)(pool + 62464);   // 2 x 4352 shorts

  const int tid  = threadIdx.x;
  const int w    = tid >> 6;
  const int l    = tid & 63;
  const int quad = l >> 4;
  const int col  = l & 15;
  const int b0   = blockIdx.x * 32;

  const int wq = w & 3;             // layer1: n-group
  const int mh = w >> 2;            // layer1: m-half
  const int v0 = w * 16;            // layer2: unit base

  // W2 -> persistent registers/AGPRs (24 short8 = 96 regs). Occupancy is
  // grid-capped at 2 waves/SIMD, so regs up to 256 cost nothing.
  const short8* const W2v = (const short8*)p.W2S;
  short8 w2r[24];
#pragma unroll
  for (int f = 0; f < 24; ++f) w2r[f] = W2v[f * 512 + tid];

  // W1 global -> LDS (48 KB)
#pragma unroll
  for (int r = 0; r < 6; ++r) {
    short8 v = *(const short8*)&p.W1G[(r * 512 + tid) * 8];
    *(short8*)&W1L[(r * 512 + tid) * 8] = v;
  }

  float b1v[4], b2v[4];
#pragma unroll
  for (int g = 0; g < 4; ++g) b1v[g] = p.WF[g * 64 + wq * 16 + col];
#pragma unroll
  for (int g = 0; g < 4; ++g) b2v[g] = p.WF[256 + g * 128 + v0 + col];

  for (int i = tid; i < 6656; i += 512) A1b[i] = 0;   // both A1 buffers
  for (int i = tid; i < 8704; i += 512) A2b[i] = 0;   // both A2 buffers
  __syncthreads();

  // x_0 -> A1 buf0; hoisted per-thread x addressing (xr,xi loop-invariant)
  int xr = 0, xi = 0;
  const bool xln = tid < 384;
  const float* xptr = p.input;
  if (xln) {
    int e = tid * 2; xr = e / 24; xi = e - xr * 24;
    const float* base = p.input + (size_t)(b0 + xr) * 2400 + xi;
    float2 xv0 = *(const float2*)base;
    *(unsigned*)&A1b[xr * 104 + xi] = cvt_pk_bf16(xv0.x, xv0.y);
    xptr = base + 24;                 // -> x_1
  }
  __syncthreads();

  f32x2 c1p[2] = {{0.f, 0.f}, {0.f, 0.f}};
  f32x2 c2p[2][2] = {{{0.f,0.f},{0.f,0.f}}, {{0.f,0.f},{0.f,0.f}}};
  f32x2 hf2p[2][2];

  float2 xv_w, xv_n;    // xv_w: value to write this step; xv_n: prefetched

  const int a1rd = (mh * 16 + col) * 104;

  // Full step: layer1 (gates1 on [x|h1_prev]) -> pointwise -> layer2
  // (gates2 on [h1_prev|h2_prev]) -> pointwise. Reads A1r/A2r, writes
  // A1w/A2w. x pipeline: write xv_w (loaded last step), prefetch xv_n.
  auto step = [&](const short* __restrict__ A1r, const short* __restrict__ A2r,
                  short* __restrict__ A1w, short* __restrict__ A2w,
                  bool w_x, bool l_x) {
    if (l_x && xln) xv_n = *(const float2*)xptr;   // x_{j+2}, used next step

    // ---- layer 1 matmul: gates1 ----
    short8 aA0 = *(const short8*)&A1r[a1rd +      quad * 8];
    short8 aA1 = *(const short8*)&A1r[a1rd + 32 + quad * 8];
    short8 aA2 = *(const short8*)&A1r[a1rd + 64 + quad * 8];
    f32x4 g1[4];
#pragma unroll
    for (int g = 0; g < 4; ++g) {
      f32x4 acc = (f32x4){b1v[g], b1v[g], b1v[g], b1v[g]};
      acc = MFMA16(aA0, *(const short8*)&W1L[(((0 * 4 + quad) << 8) + g * 64 + wq * 16 + col) * 8], acc);
      acc = MFMA16(aA1, *(const short8*)&W1L[(((1 * 4 + quad) << 8) + g * 64 + wq * 16 + col) * 8], acc);
      acc = MFMA16(aA2, *(const short8*)&W1L[(((2 * 4 + quad) << 8) + g * 64 + wq * 16 + col) * 8], acc);
      g1[g] = acc;
    }

    // ---- layer 1 pointwise (2 packed pairs) -> h1 into next buffer ----
    {
      f32x2 h01, h23;
      lstm_pair((f32x2){g1[0][0], g1[0][1]}, (f32x2){g1[1][0], g1[1][1]},
                (f32x2){g1[2][0], g1[2][1]}, (f32x2){g1[3][0], g1[3][1]},
                c1p[0], h01);
      lstm_pair((f32x2){g1[0][2], g1[0][3]}, (f32x2){g1[1][2], g1[1][3]},
                (f32x2){g1[2][2], g1[2][3]}, (f32x2){g1[3][2], g1[3][3]},
                c1p[1], h23);
      int base = (mh * 16 + quad * 4) * 104 + 32 + wq * 16 + col;
      unsigned pkA = cvt_pk_bf16(h01.x, h01.y);
      unsigned pkB = cvt_pk_bf16(h23.x, h23.y);
      A1w[base]       = (short)pkA;
      A1w[base + 104] = (short)(pkA >> 16);
      A1w[base + 208] = (short)pkB;
      A1w[base + 312] = (short)(pkB >> 16);
    }
    if (w_x && xln)
      *(unsigned*)&A1w[xr * 104 + xi] = cvt_pk_bf16(xv_w.x, xv_w.y);

    // ---- layer 2 matmul: gates2 (B-operand from registers) ----
    f32x4 g2[2][4];
#pragma unroll
    for (int g = 0; g < 4; ++g) {
      g2[0][g] = (f32x4){b2v[g], b2v[g], b2v[g], b2v[g]};
      g2[1][g] = g2[0][g];
    }
#pragma unroll
    for (int kk = 0; kk < 6; ++kk) {
      short8 a0, a1f;
      if (kk < 2) {
        a0  = *(const short8*)&A1r[      col  * 104 + 32 + kk * 32 + quad * 8];
        a1f = *(const short8*)&A1r[(16 + col) * 104 + 32 + kk * 32 + quad * 8];
      } else {
        int o = (kk - 2) * 32 + quad * 8;
        a0  = *(const short8*)&A2r[      col  * 136 + o];
        a1f = *(const short8*)&A2r[(16 + col) * 136 + o];
      }
#pragma unroll
      for (int g = 0; g < 4; ++g) {
        g2[0][g] = MFMA16(a0,  w2r[kk * 4 + g], g2[0][g]);
        g2[1][g] = MFMA16(a1f, w2r[kk * 4 + g], g2[1][g]);
      }
    }

    // ---- layer 2 pointwise (4 packed pairs) -> h2 into next buffer ----
    {
      int u2 = v0 + col;
#pragma unroll
      for (int mi = 0; mi < 2; ++mi) {
        f32x2 h01, h23;
        lstm_pair((f32x2){g2[mi][0][0], g2[mi][0][1]}, (f32x2){g2[mi][1][0], g2[mi][1][1]},
                  (f32x2){g2[mi][2][0], g2[mi][2][1]}, (f32x2){g2[mi][3][0], g2[mi][3][1]},
                  c2p[mi][0], h01);
        lstm_pair((f32x2){g2[mi][0][2], g2[mi][0][3]}, (f32x2){g2[mi][1][2], g2[mi][1][3]},
                  (f32x2){g2[mi][2][2], g2[mi][2][3]}, (f32x2){g2[mi][3][2], g2[mi][3][3]},
                  c2p[mi][1], h23);
        hf2p[mi][0] = h01;
        hf2p[mi][1] = h23;
        unsigned pkA = cvt_pk_bf16(h01.x, h01.y);
        unsigned pkB = cvt_pk_bf16(h23.x, h23.y);
        int base = (mi * 16 + quad * 4) * 136 + u2;
        A2w[base]       = (short)pkA;
        A2w[base + 136] = (short)(pkA >> 16);
        A2w[base + 272] = (short)pkB;
        A2w[base + 408] = (short)(pkB >> 16);
      }
    }
    xv_w = xv_n;
  };

  short* const A1_0 = A1b;            short* const A1_1 = A1b + 3328;
  short* const A2_0 = A2b;            short* const A2_1 = A2b + 4352;

  // ---- j=0 peeled: layer1 only (h1_0); loads x_1 (write) and x_2 (pipe) ----
  {
    if (xln) {
      xv_w = *(const float2*)xptr;            // x_1
      xv_n = *(const float2*)(xptr + 24);     // x_2
    }
    short8 aA0 = *(const short8*)&A1_0[a1rd +      quad * 8];
    short8 aA1 = *(const short8*)&A1_0[a1rd + 32 + quad * 8];
    short8 aA2 = *(const short8*)&A1_0[a1rd + 64 + quad * 8];
    f32x4 g1[4];
#pragma unroll
    for (int g = 0; g < 4; ++g) {
      f32x4 acc = (f32x4){b1v[g], b1v[g], b1v[g], b1v[g]};
      acc = MFMA16(aA0, *(const short8*)&W1L[(((0 * 4 + quad) << 8) + g * 64 + wq * 16 + col) * 8], acc);
      acc = MFMA16(aA1, *(const short8*)&W1L[(((1 * 4 + quad) << 8) + g * 64 + wq * 16 + col) * 8], acc);
      acc = MFMA16(aA2, *(const short8*)&W1L[(((2 * 4 + quad) << 8) + g * 64 + wq * 16 + col) * 8], acc);
      g1[g] = acc;
    }
    f32x2 h01, h23;
    lstm_pair((f32x2){g1[0][0], g1[0][1]}, (f32x2){g1[1][0], g1[1][1]},
              (f32x2){g1[2][0], g1[2][1]}, (f32x2){g1[3][0], g1[3][1]},
              c1p[0], h01);
    lstm_pair((f32x2){g1[0][2], g1[0][3]}, (f32x2){g1[1][2], g1[1][3]},
              (f32x2){g1[2][2], g1[2][3]}, (f32x2){g1[3][2], g1[3][3]},
              c1p[1], h23);
    int base = (mh * 16 + quad * 4) * 104 + 32 + wq * 16 + col;
    unsigned pkA = cvt_pk_bf16(h01.x, h01.y);
    unsigned pkB = cvt_pk_bf16(h23.x, h23.y);
    A1_1[base]       = (short)pkA;
    A1_1[base + 104] = (short)(pkA >> 16);
    A1_1[base + 208] = (short)pkB;
    A1_1[base + 312] = (short)(pkB >> 16);
    if (xln)
      *(unsigned*)&A1_1[xr * 104 + xi] = cvt_pk_bf16(xv_w.x, xv_w.y);
    __syncthreads();
    xv_w = xv_n;
    xptr += 48;                               // -> x_3 (prefetch target at j=1)
  }

  // ---- main loop: j = 1..100, unrolled x2 (buffer roles compile-time) ----
  for (int jj = 1; jj <= 99; jj += 2) {
    // j = jj (odd): read buf1, write buf0
    step(A1_1, A2_1, A1_0, A2_0, jj <= 98, jj <= 97);
    __syncthreads();
    xptr += 24;
    // j = jj+1 (even): read buf0, write buf1
    step(A1_0, A2_0, A1_1, A2_1, jj + 1 <= 98, jj + 1 <= 97);
    __syncthreads();
    xptr += 24;
  }

  // ---- head (fp32), aliased over W1L region ----
  float* const H2   = (float*)pool;                 // 32 x 132
  float* const FC1W = (float*)(pool + 16896);
  float* const FC2W = (float*)(pool + 20992);
  float* const FB1  = (float*)(pool + 21248);
  float* const FB2  = (float*)(pool + 21280);
  float* const OWp  = (float*)(pool + 21312);
  float* const OBp  = (float*)(pool + 21344);
  float* const X1   = (float*)(pool + 21376);
  float* const X2   = (float*)(pool + 22400);

  {
    int u2 = v0 + col;
#pragma unroll
    for (int mi = 0; mi < 2; ++mi) {
      int row = mi * 16 + quad * 4;
      H2[(row + 0) * 132 + u2] = hf2p[mi][0].x;
      H2[(row + 1) * 132 + u2] = hf2p[mi][0].y;
      H2[(row + 2) * 132 + u2] = hf2p[mi][1].x;
      H2[(row + 3) * 132 + u2] = hf2p[mi][1].y;
    }
  }
  for (int i = tid; i < 1024; i += 512) FC1W[i] = p.WF[768 + i];
  if (tid < 64)               FC2W[tid]     = p.WF[1792 + tid];
  if (tid >= 64 && tid < 72)  FB1[tid - 64] = p.WF[1856 + tid - 64];
  if (tid >= 72 && tid < 80)  FB2[tid - 72] = p.WF[1864 + tid - 72];
  if (tid >= 80 && tid < 88)  OWp[tid - 80] = p.WF[1872 + tid - 80];
  if (tid == 88)              OBp[0]        = p.WF[1880];
  __syncthreads();

  if (tid < 256) {
    int row = tid >> 3, o = tid & 7;
    float s = FB1[o];
#pragma unroll 8
    for (int k = 0; k < 128; ++k) s += H2[row * 132 + k] * FC1W[o * 128 + k];
    X1[tid] = fmaxf(s, 0.0f);
  }
  __syncthreads();
  if (tid < 256) {
    int row = tid >> 3, o = tid & 7;
    float s = FB2[o];
#pragma unroll
    for (int k = 0; k < 8; ++k) s += X1[row * 8 + k] * FC2W[o * 8 + k];
    X2[tid] = fmaxf(s, 0.0f);
  }
  __syncthreads();
  if (tid < 32) {
    float s = OBp[0];
#pragma unroll
    for (int k = 0; k < 8; ++k) s += X2[tid * 8 + k] * OWp[k];
    p.out[b0 + tid] = s;
  }
}

extern "C" void kernel_launch(void* const* d_in, const int* in_sizes, int n_in,
                              void* d_out, int out_size, void* d_ws, size_t ws_size,
                              hipStream_t stream)
{
  (void)in_sizes; (void)n_in; (void)ws_size; (void)out_size;

  SampParams sp;
  const float** grp[12] = { sp.w1i, sp.w1h, sp.b1, sp.w2i, sp.w2h, sp.b2,
                            sp.f1w, sp.f1b, sp.f2w, sp.f2b, sp.ow, sp.ob };
  int idx = 1;
  for (int t = 0; t < 12; ++t)
    for (int j = 0; j < 3; ++j)
      grp[t][j] = (const float*)d_in[idx++];
  sp.W2S = (short*)d_ws;
  sp.W1G = (short*)((char*)d_ws + WS_W1G_OFF);
  sp.WF  = (float*)((char*)d_ws + WS_WF_OFF);

  LstmParams bp;
  bp.input = (const float*)d_in[0];
  bp.W2S = (const short*)d_ws;
  bp.W1G = (const short*)((char*)d_ws + WS_W1G_OFF);
  bp.WF  = (const float*)((char*)d_ws + WS_WF_OFF);
  bp.out = (float*)d_out;

  sample_kernel<<<dim3(116), dim3(256), 0, stream>>>(sp);
  blstm_kernel<<<dim3(256), dim3(512), 0, stream>>>(bp);
}

// Round 5
// 410.001 us; speedup vs baseline: 1.0159x; 1.0159x over previous
//
#include <hip/hip_runtime.h>
#include <math.h>

// Bayesian 2-layer LSTM (B=8192,T=100,I=24,H=64,H2=128) — two-kernel version.
//
// R10: R8 structure (measured 286 us) + strictly-local trans reduction.
// R9 lesson: cross-element restructuring added chain latency that cancelled
// issue savings. Here all changes are local:
// (1) lstm_quad: fuse the two per-element rcps into one R=rcp(A*B*C*D)
//     (1/A = R*Q*B etc., same algebra, +3 muls, -1 rcp). Safe unless
//     combined |gates| > ~88 (data: ~10).
// (2) E-rcp paired across element pairs with cn clamped to +-15 on the
//     E-path only (tanh(15)==1 in f32; E-products < 2^87, overflow-proof).
//     Net per elem: 5 exp2 + 1.5 rcp (R8: 5 exp2 + 3 rcp).
// (3) Hot barriers = "s_waitcnt lgkmcnt(0); s_barrier" (no vmcnt drain) +
//     x prefetched one full step early -> global x loads span barriers.
// (4) sample_kernel back to R8 form (68 blocks; R9 split changed nothing).

typedef __attribute__((ext_vector_type(8))) short short8;   // 8 bf16
typedef __attribute__((ext_vector_type(4))) float f32x4;

#define MFMA16(a, b, c) __builtin_amdgcn_mfma_f32_16x16x32_bf16((a), (b), (c), 0, 0, 0)

// Hot-loop barrier: drain LDS only; vmcnt (x prefetch) stays in flight.
#define BARRIER() asm volatile("s_waitcnt lgkmcnt(0)\n\ts_barrier" ::: "memory")

// ---- d_ws layout (bytes) ----
// [0, 196608)        W2S : 12288 short8 frags, idx = (kk*4+g)*512 + tid
// [196608, 245760)   W1G : 3072 short8, u = slice*256+n (slice = kk*4+quad)
// [245760, 253284)   WF  : 1881 floats: b1[256] b2[512] fc1w[1024] fc2w[64]
//                          fc1b[8] fc2b[8] ow[8] ob[1]
#define WS_W1G_OFF 196608
#define WS_WF_OFF  245760

struct SampParams {
  const float* w1i[3]; const float* w1h[3]; const float* b1[3];
  const float* w2i[3]; const float* w2h[3]; const float* b2[3];
  const float* f1w[3]; const float* f1b[3];
  const float* f2w[3]; const float* f2b[3];
  const float* ow[3];  const float* ob[3];
  short* W2S; short* W1G; float* WF;
};

struct LstmParams {
  const float* input;
  const short* W2S; const short* W1G; const float* WF;
  float* out;
};

__device__ __forceinline__ float softplus_fast(float x) {
  // log(1+e^x) = ln2 * log2(1 + 2^(x*log2e))
  float e = __builtin_amdgcn_exp2f(1.44269504f * x);
  return 0.69314718f * __builtin_amdgcn_logf(1.0f + e);
}

__device__ __forceinline__ float samp(const float* const q[3], int idx) {
  return q[0][idx] + softplus_fast(q[1][idx]) * q[2][idx];
}

__device__ __forceinline__ short f2bf(float f) {
  unsigned u = __float_as_uint(f);
  unsigned r = (u + 0x7FFFu + ((u >> 16) & 1u)) >> 16;   // RNE
  return (short)r;
}

__device__ __forceinline__ unsigned cvt_pk_bf16(float lo, float hi) {
  unsigned r;
  asm("v_cvt_pk_bf16_f32 %0, %1, %2" : "=v"(r) : "v"(lo), "v"(hi));
  return r;
}

// Four LSTM elements. Gates (i,f,g,o) per element -> new cell c, hidden h.
//   sig(i)=1/A, A=1+exp2(-K*i);  tanh(g)=1-2/C, C=1+exp2(2K*g)
// Per element: P=A*B, Q=C*D, R=rcp(P*Q):
//   si=R*Q*B, sf=R*Q*A, tg=1-2*(R*P*D), so=R*P*C   (one rcp, not two)
// h: E=1+exp2(2K*clamp(cn,15)); rcp paired across elements (E0E1),(E2E3).
// Per element: 5 exp2 + 1.5 rcp (R8 was 5 + 3). Cell chains independent.
__device__ __forceinline__ void lstm_quad(const f32x4 gi, const f32x4 gf,
                                          const f32x4 gg, const f32x4 go,
                                          float* c, float* h) {
  float E[4], so[4];
#pragma unroll
  for (int i = 0; i < 4; ++i) {
    float a  = __builtin_amdgcn_exp2f(-1.44269504f * gi[i]);
    float b  = __builtin_amdgcn_exp2f(-1.44269504f * gf[i]);
    float cv = __builtin_amdgcn_exp2f( 2.88539008f * gg[i]);
    float d  = __builtin_amdgcn_exp2f(-1.44269504f * go[i]);
    float A = 1.0f + a, B = 1.0f + b, C = 1.0f + cv, D = 1.0f + d;
    float P = A * B, Q = C * D;
    float R = __builtin_amdgcn_rcpf(P * Q);
    float RQ = R * Q, RP = R * P;
    float si = RQ * B;                 // sig(i) = 1/A
    float sf = RQ * A;                 // sig(f) = 1/B
    float tg = 1.0f - 2.0f * (RP * D); // tanh(g) = 1-2/C
    so[i]    = RP * C;                 // sig(o) = 1/D
    float cn = sf * c[i] + si * tg;
    c[i] = cn;
    float cc = fminf(fmaxf(cn, -15.0f), 15.0f);
    E[i] = 1.0f + __builtin_amdgcn_exp2f(2.88539008f * cc);
  }
  float R01 = __builtin_amdgcn_rcpf(E[0] * E[1]);
  float R23 = __builtin_amdgcn_rcpf(E[2] * E[3]);
  h[0] = so[0] * (1.0f - 2.0f * (R01 * E[1]));
  h[1] = so[1] * (1.0f - 2.0f * (R01 * E[0]));
  h[2] = so[2] * (1.0f - 2.0f * (R23 * E[3]));
  h[3] = so[3] * (1.0f - 2.0f * (R23 * E[2]));
}

// ---------------- kernel 1: sample all weights into d_ws ----------------
__global__ __launch_bounds__(256) void sample_kernel(SampParams p)
{
  int i = blockIdx.x * 256 + threadIdx.x;
  if (i < 12288) {
    int tid = i & 511, gg = (i >> 9) & 3, kk = i >> 11;
    int quad = (tid >> 4) & 3, col = tid & 15, v0 = (tid >> 6) * 16;
    int c = gg * 128 + v0 + col;
    short8 v;
#pragma unroll
    for (int j = 0; j < 8; ++j) {
      int k = kk * 32 + quad * 8 + j;
      float x = (k < 64) ? samp(p.w2i, k * 512 + c) : samp(p.w2h, (k - 64) * 512 + c);
      v[j] = f2bf(x);
    }
    *(short8*)&p.W2S[i * 8] = v;
  } else if (i < 15360) {
    int u = i - 12288;
    int slice = u >> 8, n = u & 255;
    int k0 = (slice >> 2) * 32 + (slice & 3) * 8;
    short8 v;
#pragma unroll
    for (int j = 0; j < 8; ++j) {
      int k = k0 + j;
      float x = 0.0f;
      if (k < 24)       x = samp(p.w1i, k * 256 + n);
      else if (k >= 32) x = samp(p.w1h, (k - 32) * 256 + n);
      v[j] = f2bf(x);
    }
    *(short8*)&p.W1G[u * 8] = v;
  } else if (i < 17241) {
    int u = i - 15360;
    float x;
    if (u < 256)       x = samp(p.b1,  u);
    else if (u < 768)  x = samp(p.b2,  u - 256);
    else if (u < 1792) x = samp(p.f1w, u - 768);
    else if (u < 1856) x = samp(p.f2w, u - 1792);
    else if (u < 1864) x = samp(p.f1b, u - 1856);
    else if (u < 1872) x = samp(p.f2b, u - 1864);
    else if (u < 1880) x = samp(p.ow,  u - 1872);
    else               x = samp(p.ob,  0);
    p.WF[u] = x;
  }
}

// ---------------- kernel 2: fused 2-layer LSTM + head ----------------
// LDS pool:
//   [0,49152)      W1L : W1cat bf16 (3072 short8)
//   [49152,62464)  A1  : 2 buf x (32 x 104 shorts) [x(24)|pad(8)|h1(64)]
//   [62464,79872)  A2  : 2 buf x (32 x 136 shorts) [h2(128)|pad]
// Head phase aliases [0,...) : H2 32x132 f32, FC1W, FC2W, FB1/FB2/OW/OB, X1, X2

__global__ __launch_bounds__(512, 2)
void blstm_kernel(LstmParams p)
{
  __shared__ __align__(16) unsigned char pool[79872];
  short* const W1L = (short*)pool;
  short* const A1b = (short*)(pool + 49152);   // 2 x 3328 shorts
  short* const A2b = (short*)(pool + 62464);   // 2 x 4352 shorts

  const int tid  = threadIdx.x;
  const int w    = tid >> 6;
  const int l    = tid & 63;
  const int quad = l >> 4;
  const int col  = l & 15;
  const int b0   = blockIdx.x * 32;

  const int wq = w & 3;             // layer1: n-group
  const int mh = w >> 2;            // layer1: m-half
  const int v0 = w * 16;            // layer2: unit base

  // W2 -> persistent registers/AGPRs (24 short8 = 96 regs). Occupancy is
  // grid-capped at 2 waves/SIMD, so regs up to 256 cost nothing.
  const short8* const W2v = (const short8*)p.W2S;
  short8 w2r[24];
#pragma unroll
  for (int f = 0; f < 24; ++f) w2r[f] = W2v[f * 512 + tid];

  // W1 global -> LDS (48 KB)
#pragma unroll
  for (int r = 0; r < 6; ++r) {
    short8 v = *(const short8*)&p.W1G[(r * 512 + tid) * 8];
    *(short8*)&W1L[(r * 512 + tid) * 8] = v;
  }

  float b1v[4], b2v[4];
#pragma unroll
  for (int g = 0; g < 4; ++g) b1v[g] = p.WF[g * 64 + wq * 16 + col];
#pragma unroll
  for (int g = 0; g < 4; ++g) b2v[g] = p.WF[256 + g * 128 + v0 + col];

  for (int i = tid; i < 6656; i += 512) A1b[i] = 0;   // both A1 buffers
  for (int i = tid; i < 8704; i += 512) A2b[i] = 0;   // both A2 buffers
  __syncthreads();

  // x_0 -> A1 buf0; hoisted per-thread x addressing (xr,xi loop-invariant)
  int xr = 0, xi = 0;
  const bool xln = tid < 384;
  const float* xptr = p.input;
  if (xln) {
    int e = tid * 2; xr = e / 24; xi = e - xr * 24;
    const float* base = p.input + (size_t)(b0 + xr) * 2400 + xi;
    float2 xv0 = *(const float2*)base;
    *(unsigned*)&A1b[xr * 104 + xi] = cvt_pk_bf16(xv0.x, xv0.y);
    xptr = base + 24;                 // -> x_1
  }
  __syncthreads();

  float c1a[4]    = {0.f, 0.f, 0.f, 0.f};
  float c2a[2][4] = {{0.f,0.f,0.f,0.f},{0.f,0.f,0.f,0.f}};
  float hf2[2][4];

  float2 xv_w, xv_n;    // xv_w: written this step; xv_n: prefetched (step+1)

  const int a1rd = (mh * 16 + col) * 104;

  // Full step: layer1 (gates1 on [x|h1_prev]) -> pointwise -> layer2
  // (gates2 on [h1_prev|h2_prev]) -> pointwise. Reads A1r/A2r, writes
  // A1w/A2w. x pipeline: write xv_w (loaded last step), prefetch xv_n.
  auto step = [&](const short* __restrict__ A1r, const short* __restrict__ A2r,
                  short* __restrict__ A1w, short* __restrict__ A2w,
                  bool w_x, bool l_x) {
    if (l_x && xln) xv_n = *(const float2*)xptr;   // x_{j+2}, used next step

    // ---- layer 1 matmul: gates1 ----
    short8 aA0 = *(const short8*)&A1r[a1rd +      quad * 8];
    short8 aA1 = *(const short8*)&A1r[a1rd + 32 + quad * 8];
    short8 aA2 = *(const short8*)&A1r[a1rd + 64 + quad * 8];
    f32x4 g1[4];
#pragma unroll
    for (int g = 0; g < 4; ++g) {
      f32x4 acc = (f32x4){b1v[g], b1v[g], b1v[g], b1v[g]};
      acc = MFMA16(aA0, *(const short8*)&W1L[(((0 * 4 + quad) << 8) + g * 64 + wq * 16 + col) * 8], acc);
      acc = MFMA16(aA1, *(const short8*)&W1L[(((1 * 4 + quad) << 8) + g * 64 + wq * 16 + col) * 8], acc);
      acc = MFMA16(aA2, *(const short8*)&W1L[(((2 * 4 + quad) << 8) + g * 64 + wq * 16 + col) * 8], acc);
      g1[g] = acc;
    }

    // ---- layer 1 pointwise -> h1 into next buffer ----
    {
      float h1v[4];
      lstm_quad(g1[0], g1[1], g1[2], g1[3], c1a, h1v);
      int base = (mh * 16 + quad * 4) * 104 + 32 + wq * 16 + col;
      unsigned pkA = cvt_pk_bf16(h1v[0], h1v[1]);
      unsigned pkB = cvt_pk_bf16(h1v[2], h1v[3]);
      A1w[base]       = (short)pkA;
      A1w[base + 104] = (short)(pkA >> 16);
      A1w[base + 208] = (short)pkB;
      A1w[base + 312] = (short)(pkB >> 16);
    }
    if (w_x && xln)
      *(unsigned*)&A1w[xr * 104 + xi] = cvt_pk_bf16(xv_w.x, xv_w.y);

    // ---- layer 2 matmul: gates2 (B-operand from registers) ----
    f32x4 g2[2][4];
#pragma unroll
    for (int g = 0; g < 4; ++g) {
      g2[0][g] = (f32x4){b2v[g], b2v[g], b2v[g], b2v[g]};
      g2[1][g] = g2[0][g];
    }
#pragma unroll
    for (int kk = 0; kk < 6; ++kk) {
      short8 a0, a1f;
      if (kk < 2) {
        a0  = *(const short8*)&A1r[      col  * 104 + 32 + kk * 32 + quad * 8];
        a1f = *(const short8*)&A1r[(16 + col) * 104 + 32 + kk * 32 + quad * 8];
      } else {
        int o = (kk - 2) * 32 + quad * 8;
        a0  = *(const short8*)&A2r[      col  * 136 + o];
        a1f = *(const short8*)&A2r[(16 + col) * 136 + o];
      }
#pragma unroll
      for (int g = 0; g < 4; ++g) {
        g2[0][g] = MFMA16(a0,  w2r[kk * 4 + g], g2[0][g]);
        g2[1][g] = MFMA16(a1f, w2r[kk * 4 + g], g2[1][g]);
      }
    }

    // ---- layer 2 pointwise -> h2 into next buffer ----
    {
      int u2 = v0 + col;
#pragma unroll
      for (int mi = 0; mi < 2; ++mi) {
        float hv[4];
        lstm_quad(g2[mi][0], g2[mi][1], g2[mi][2], g2[mi][3], c2a[mi], hv);
#pragma unroll
        for (int i = 0; i < 4; ++i) hf2[mi][i] = hv[i];
        unsigned pkA = cvt_pk_bf16(hv[0], hv[1]);
        unsigned pkB = cvt_pk_bf16(hv[2], hv[3]);
        int base = (mi * 16 + quad * 4) * 136 + u2;
        A2w[base]       = (short)pkA;
        A2w[base + 136] = (short)(pkA >> 16);
        A2w[base + 272] = (short)pkB;
        A2w[base + 408] = (short)(pkB >> 16);
      }
    }
    xv_w = xv_n;
  };

  short* const A1_0 = A1b;            short* const A1_1 = A1b + 3328;
  short* const A2_0 = A2b;            short* const A2_1 = A2b + 4352;

  // ---- j=0 peeled: layer1 only (h1_0); loads x_1 (write) and x_2 (pipe) ----
  {
    if (xln) {
      xv_w = *(const float2*)xptr;            // x_1
      xv_n = *(const float2*)(xptr + 24);     // x_2
    }
    short8 aA0 = *(const short8*)&A1_0[a1rd +      quad * 8];
    short8 aA1 = *(const short8*)&A1_0[a1rd + 32 + quad * 8];
    short8 aA2 = *(const short8*)&A1_0[a1rd + 64 + quad * 8];
    f32x4 g1[4];
#pragma unroll
    for (int g = 0; g < 4; ++g) {
      f32x4 acc = (f32x4){b1v[g], b1v[g], b1v[g], b1v[g]};
      acc = MFMA16(aA0, *(const short8*)&W1L[(((0 * 4 + quad) << 8) + g * 64 + wq * 16 + col) * 8], acc);
      acc = MFMA16(aA1, *(const short8*)&W1L[(((1 * 4 + quad) << 8) + g * 64 + wq * 16 + col) * 8], acc);
      acc = MFMA16(aA2, *(const short8*)&W1L[(((2 * 4 + quad) << 8) + g * 64 + wq * 16 + col) * 8], acc);
      g1[g] = acc;
    }
    float h1v[4];
    lstm_quad(g1[0], g1[1], g1[2], g1[3], c1a, h1v);
    int base = (mh * 16 + quad * 4) * 104 + 32 + wq * 16 + col;
    unsigned pkA = cvt_pk_bf16(h1v[0], h1v[1]);
    unsigned pkB = cvt_pk_bf16(h1v[2], h1v[3]);
    A1_1[base]       = (short)pkA;
    A1_1[base + 104] = (short)(pkA >> 16);
    A1_1[base + 208] = (short)pkB;
    A1_1[base + 312] = (short)(pkB >> 16);
    if (xln)
      *(unsigned*)&A1_1[xr * 104 + xi] = cvt_pk_bf16(xv_w.x, xv_w.y);
    BARRIER();
    xv_w = xv_n;
    xptr += 48;                               // -> x_3 (prefetch target at j=1)
  }

  // ---- main loop: j = 1..100, unrolled x2 (buffer roles compile-time) ----
  for (int jj = 1; jj <= 99; jj += 2) {
    // j = jj (odd): read buf1, write buf0
    step(A1_1, A2_1, A1_0, A2_0, jj <= 98, jj <= 97);
    BARRIER();
    xptr += 24;
    // j = jj+1 (even): read buf0, write buf1
    step(A1_0, A2_0, A1_1, A2_1, jj + 1 <= 98, jj + 1 <= 97);
    BARRIER();
    xptr += 24;
  }

  // ---- head (fp32), aliased over W1L region ----
  float* const H2   = (float*)pool;                 // 32 x 132
  float* const FC1W = (float*)(pool + 16896);
  float* const FC2W = (float*)(pool + 20992);
  float* const FB1  = (float*)(pool + 21248);
  float* const FB2  = (float*)(pool + 21280);
  float* const OWp  = (float*)(pool + 21312);
  float* const OBp  = (float*)(pool + 21344);
  float* const X1   = (float*)(pool + 21376);
  float* const X2   = (float*)(pool + 22400);

  {
    int u2 = v0 + col;
#pragma unroll
    for (int mi = 0; mi < 2; ++mi)
#pragma unroll
      for (int i = 0; i < 4; ++i) {
        int row = mi * 16 + quad * 4 + i;
        H2[row * 132 + u2] = hf2[mi][i];   // h2_99
      }
  }
  for (int i = tid; i < 1024; i += 512) FC1W[i] = p.WF[768 + i];
  if (tid < 64)               FC2W[tid]     = p.WF[1792 + tid];
  if (tid >= 64 && tid < 72)  FB1[tid - 64] = p.WF[1856 + tid - 64];
  if (tid >= 72 && tid < 80)  FB2[tid - 72] = p.WF[1864 + tid - 72];
  if (tid >= 80 && tid < 88)  OWp[tid - 80] = p.WF[1872 + tid - 80];
  if (tid == 88)              OBp[0]        = p.WF[1880];
  __syncthreads();

  if (tid < 256) {
    int row = tid >> 3, o = tid & 7;
    float s = FB1[o];
#pragma unroll 8
    for (int k = 0; k < 128; ++k) s += H2[row * 132 + k] * FC1W[o * 128 + k];
    X1[tid] = fmaxf(s, 0.0f);
  }
  __syncthreads();
  if (tid < 256) {
    int row = tid >> 3, o = tid & 7;
    float s = FB2[o];
#pragma unroll
    for (int k = 0; k < 8; ++k) s += X1[row * 8 + k] * FC2W[o * 8 + k];
    X2[tid] = fmaxf(s, 0.0f);
  }
  __syncthreads();
  if (tid < 32) {
    float s = OBp[0];
#pragma unroll
    for (int k = 0; k < 8; ++k) s += X2[tid * 8 + k] * OWp[k];
    p.out[b0 + tid] = s;
  }
}

extern "C" void kernel_launch(void* const* d_in, const int* in_sizes, int n_in,
                              void* d_out, int out_size, void* d_ws, size_t ws_size,
                              hipStream_t stream)
{
  (void)in_sizes; (void)n_in; (void)ws_size; (void)out_size;

  SampParams sp;
  const float** grp[12] = { sp.w1i, sp.w1h, sp.b1, sp.w2i, sp.w2h, sp.b2,
                            sp.f1w, sp.f1b, sp.f2w, sp.f2b, sp.ow, sp.ob };
  int idx = 1;
  for (int t = 0; t < 12; ++t)
    for (int j = 0; j < 3; ++j)
      grp[t][j] = (const float*)d_in[idx++];
  sp.W2S = (short*)d_ws;
  sp.W1G = (short*)((char*)d_ws + WS_W1G_OFF);
  sp.WF  = (float*)((char*)d_ws + WS_WF_OFF);

  LstmParams bp;
  bp.input = (const float*)d_in[0];
  bp.W2S = (const short*)d_ws;
  bp.W1G = (const short*)((char*)d_ws + WS_W1G_OFF);
  bp.WF  = (const float*)((char*)d_ws + WS_WF_OFF);
  bp.out = (float*)d_out;

  sample_kernel<<<dim3(68), dim3(256), 0, stream>>>(sp);
  blstm_kernel<<<dim3(256), dim3(512), 0, stream>>>(bp);
}